// Round 1
// baseline (1168.066 us; speedup 1.0000x reference)
//
#include <hip/hip_runtime.h>

// BinaryTree hierarchical-sigmoid product.
//   B = 65536 items, D = 128, DEPTH = 20 (21 levels), W: [2^21-1, 128] fp32.
//   prob[b] = prod_i sigmoid( dot(W[path_i(ctx)], W[leaf(inp)]) )
// Layout: 16 lanes per item (8 floats/lane = two float4), 4 items per wave.
// Reduction: 4-step shfl_xor within the 16-lane group (masks 1,2,4,8 stay
// in-group). sigmoid product via s = prod(1+exp(-l)); prob = 1/s.

#define TREE_DEPTH 20
#define TREE_OFFSET ((1u << TREE_DEPTH) - 1u)   // 1048575
#define NDIM 128

__global__ __launch_bounds__(256) void binary_tree_kernel(
    const int* __restrict__ col,      // [B,2] int32
    const float* __restrict__ W,      // [SIZE,128] fp32
    float* __restrict__ out,          // [B] fp32
    int B)
{
    const int lane = threadIdx.x & 63;
    const int wid  = blockIdx.x * (blockDim.x >> 6) + (threadIdx.x >> 6);
    const int grp  = lane >> 4;   // 0..3: which item within the wave
    const int sub  = lane & 15;   // 0..15: position within the 16-lane group
    const int item = wid * 4 + grp;
    if (item >= B) return;

    const int c0 = col[2 * item];
    const int c1 = col[2 * item + 1];

    // z = W[leaf of input vertex]; lane holds floats [sub*4, sub*4+4) and
    // [64+sub*4, ...): two contiguous 256B half-row segments per group.
    const float* zrow = W + (size_t)((unsigned)c0 + TREE_OFFSET) * NDIM;
    const float4 za = *(const float4*)(zrow + sub * 4);
    const float4 zb = *(const float4*)(zrow + 64 + sub * 4);

    const unsigned b1 = (unsigned)c1 + TREE_OFFSET + 1u;  // 1-based leaf id

    // Prefetch level 0 (root) row.
    unsigned idx = (b1 >> TREE_DEPTH) - 1u;
    const float* prow = W + (size_t)idx * NDIM;
    float4 wa = *(const float4*)(prow + sub * 4);
    float4 wb = *(const float4*)(prow + 64 + sub * 4);

    float s = 1.0f;
    for (int i = 0; i <= TREE_DEPTH; ++i) {
        float4 na, nb;
        if (i < TREE_DEPTH) {
            const unsigned nidx = (b1 >> (TREE_DEPTH - (i + 1))) - 1u;
            const float* nrow = W + (size_t)nidx * NDIM;
            na = *(const float4*)(nrow + sub * 4);
            nb = *(const float4*)(nrow + 64 + sub * 4);
        }
        // partial dot: 8 fma/lane
        float p = wa.x * za.x + wa.y * za.y + wa.z * za.z + wa.w * za.w
                + wb.x * zb.x + wb.y * zb.y + wb.z * zb.z + wb.w * zb.w;
        // 16-lane group reduction (4 items reduced per wave instruction)
        p += __shfl_xor(p, 1);
        p += __shfl_xor(p, 2);
        p += __shfl_xor(p, 4);
        p += __shfl_xor(p, 8);
        // sigmoid(l) = 1/(1+exp(-l)); accumulate the denominator product
        s *= (1.0f + __expf(-p));
        wa = na; wb = nb;
    }

    if (sub == 0) out[item] = 1.0f / s;
}

extern "C" void kernel_launch(void* const* d_in, const int* in_sizes, int n_in,
                              void* d_out, int out_size, void* d_ws, size_t ws_size,
                              hipStream_t stream) {
    const int*   col = (const int*)d_in[0];    // collocation [B,2] int32
    const float* W   = (const float*)d_in[1];  // [SIZE,128] fp32
    float*       out = (float*)d_out;

    const int B = in_sizes[0] / 2;             // 65536
    const int items_per_block = 16;            // 256 threads = 4 waves x 4 items
    const int grid = (B + items_per_block - 1) / items_per_block;

    binary_tree_kernel<<<grid, 256, 0, stream>>>(col, W, out, B);
}